// Round 2
// baseline (2405.476 us; speedup 1.0000x reference)
//
#include <hip/hip_runtime.h>

typedef __bf16 bf16x4 __attribute__((ext_vector_type(4)));
typedef __bf16 bf16x8 __attribute__((ext_vector_type(8)));
typedef float  f32x4  __attribute__((ext_vector_type(4)));

#define THREADS 256
constexpr int BM = 128, BN = 128, BK = 32, BKP = 40;

// ---- workspace layout (bytes) ----
constexpr size_t MB = 1024*1024;
constexpr size_t oXN1 = 0;          // f32 [1024,2048]  8 MB (rmsnorm1 out)
constexpr size_t oQF  = 8*MB;       // f32 q [1024,16,128]
constexpr size_t oKF  = 16*MB;
constexpr size_t oVF  = 24*MB;
constexpr size_t oSC  = 32*MB;      // f32 scores/P [32,512,512] 32 MB
constexpr size_t oATT = 64*MB;      // f32 attn out [1024,2048] 8 MB
constexpr size_t oH2  = 72*MB;      // f32 h + attn  8 MB
constexpr size_t oXB2 = 80*MB;      // bf16 rmsnorm2 4 MB
constexpr size_t oRT  = 84*MB;      // routing scratch
// MoE overlay in [0, 64MB) — xn1/q/k/v/scores dead by then
constexpr size_t oG   = 0;          // f32 [2048,1024] 8 MB
constexpr size_t oU   = 8*MB;
constexpr size_t oHB  = 16*MB;      // bf16 [2048,1024] 4 MB
constexpr size_t oY   = 20*MB;      // f32 [2048,2048] 16 MB
constexpr size_t oSG  = 36*MB;      // f32 [1024,1024] 4 MB
constexpr size_t oSU  = 40*MB;
constexpr size_t oSH  = 44*MB;      // bf16 [1024,1024] 2 MB
constexpr size_t oSD  = 46*MB;      // f32 [1024,2048] 8 MB (ends 54 MB)
// routing arrays
constexpr size_t oEIDX = oRT;
constexpr size_t oEW   = oRT + 8192;
constexpr size_t oSLOT = oRT + 16384;
constexpr size_t oLIST = oRT + 24576;
constexpr size_t oCNT  = oRT + 32768;
constexpr size_t oOFF  = oRT + 33024;
constexpr size_t oCUR  = oRT + 33280;

__device__ __forceinline__ bf16x4 ld4cvt(const float* p) {
  f32x4 v = *(const f32x4*)p;
  bf16x4 r; r[0]=(__bf16)v[0]; r[1]=(__bf16)v[1]; r[2]=(__bf16)v[2]; r[3]=(__bf16)v[3];
  return r;
}
__device__ __forceinline__ bf16x4 ld4cvt(const __bf16* p) { return *(const bf16x4*)p; }

// MODE 0: batched strided; MODE 1: expert w/ gathered A rows; MODE 2: expert, dense A rows
// SPLIT: fp32 operands decomposed hi+lo bf16, 3-term MFMA (fp32-like precision)
template<int MODE, bool SPLIT, typename AT, typename BT, bool TRANSB, bool RESID, bool CAUSAL, bool KTRI>
__global__ __launch_bounds__(256, 2)
void gemm_kernel(const AT* __restrict__ A, const BT* __restrict__ B, float* __restrict__ C,
                 const float* __restrict__ Rres,
                 int M, int N, int K, int lda, int ldb, int ldc,
                 int zlo, long aHi, long aLo, long bHi, long bLo, long cHi, long cLo,
                 const int* __restrict__ counts, const int* __restrict__ offsets,
                 const int* __restrict__ gather)
{
  const int n0 = blockIdx.x * BN;
  const int m0 = blockIdx.y * BM;
  const int z  = blockIdx.z;
  if (CAUSAL && n0 > m0) return;   // fully-masked score tile

  int mcount; int rowbase = 0;
  const AT* Ab = A; const BT* Bb = B; long coff = 0;
  if constexpr (MODE == 0) {
    mcount = M;
    int zh = z / zlo, zl = z % zlo;
    Ab = A + (long)zh*aHi + (long)zl*aLo;
    Bb = B + (long)zh*bHi + (long)zl*bLo;
    coff = (long)zh*cHi + (long)zl*cLo;
  } else {
    mcount = counts[z];
    rowbase = offsets[z];
    if (m0 >= mcount) return;
    Bb = B + (long)z*bHi;
  }

  constexpr int ABUF = BM*BKP;
  constexpr int BBUF = BN*BKP;
  __shared__ __align__(16) __bf16 As[(SPLIT?2:1)*ABUF];
  __shared__ __align__(16) __bf16 Bs[(SPLIT?2:1)*BBUF];

  const int tid = threadIdx.x;
  const int lane = tid & 63, wave = tid >> 6;
  const int wm = wave >> 1, wn = wave & 1;
  const int lq = lane >> 4, lr = lane & 15;

  int kend = K;
  if (KTRI) { int ke = m0 + BM; kend = ke < K ? ke : K; }

  f32x4 acc[4][4] = {};

  for (int k0 = 0; k0 < kend; k0 += BK) {
    if (k0) __syncthreads();
    // stage A tile [BM][BK] -> As (m-major, K-contig)
#pragma unroll
    for (int it = 0; it < 4; ++it) {
      int lin = tid + it*THREADS;
      int row = lin >> 3;
      int c4  = (lin & 7) << 2;
      int gr  = m0 + row;
      bf16x4 hi; bf16x4 lo;
      hi[0]=hi[1]=hi[2]=hi[3]=(__bf16)0.0f;
      lo[0]=lo[1]=lo[2]=lo[3]=(__bf16)0.0f;
      if (gr < mcount) {
        long arow;
        if constexpr (MODE == 1) arow = gather[rowbase + gr];
        else if constexpr (MODE == 2) arow = rowbase + gr;
        else arow = gr;
        const AT* p = Ab + arow*(long)lda + k0 + c4;
        if constexpr (SPLIT) {
          f32x4 v = *(const f32x4*)p;
#pragma unroll
          for (int j = 0; j < 4; ++j) {
            hi[j] = (__bf16)v[j];
            lo[j] = (__bf16)(v[j] - (float)hi[j]);
          }
        } else {
          hi = ld4cvt(p);
        }
      }
      *(bf16x4*)(As + row*BKP + c4) = hi;
      if constexpr (SPLIT) *(bf16x4*)(As + ABUF + row*BKP + c4) = lo;
    }
    // stage B tile -> Bs (n-major, K-contig)
    if constexpr (TRANSB) {
#pragma unroll
      for (int it = 0; it < 4; ++it) {
        int lin = tid + it*THREADS;
        int row = lin >> 3;
        int c4  = (lin & 7) << 2;
        const BT* p = Bb + (long)(n0+row)*ldb + k0 + c4;
        if constexpr (SPLIT) {
          f32x4 v = *(const f32x4*)p;
          bf16x4 hi, lo;
#pragma unroll
          for (int j = 0; j < 4; ++j) {
            hi[j] = (__bf16)v[j];
            lo[j] = (__bf16)(v[j] - (float)hi[j]);
          }
          *(bf16x4*)(Bs + row*BKP + c4) = hi;
          *(bf16x4*)(Bs + BBUF + row*BKP + c4) = lo;
        } else {
          *(bf16x4*)(Bs + row*BKP + c4) = ld4cvt(p);
        }
      }
    } else {
#pragma unroll
      for (int it = 0; it < 4; ++it) {
        int lin = tid + it*THREADS;
        int kk = lin >> 5;
        int nn = (lin & 31) << 2;
        const BT* p = Bb + (long)(k0+kk)*ldb + n0 + nn;
        if constexpr (SPLIT) {
          f32x4 v = *(const f32x4*)p;
#pragma unroll
          for (int j = 0; j < 4; ++j) {
            __bf16 h = (__bf16)v[j];
            Bs[(nn+j)*BKP + kk] = h;
            Bs[BBUF + (nn+j)*BKP + kk] = (__bf16)(v[j] - (float)h);
          }
        } else {
          bf16x4 v = ld4cvt(p);
#pragma unroll
          for (int j = 0; j < 4; ++j) Bs[(nn+j)*BKP + kk] = v[j];
        }
      }
    }
    __syncthreads();

    bf16x8 fa[4], fal[4];
    const __bf16* ap = As + (wm*64 + lr)*BKP + lq*8;
    const __bf16* bp = Bs + (wn*64 + lr)*BKP + lq*8;
#pragma unroll
    for (int i = 0; i < 4; ++i) {
      fa[i] = *(const bf16x8*)(ap + i*16*BKP);
      if constexpr (SPLIT) fal[i] = *(const bf16x8*)(ap + ABUF + i*16*BKP);
    }
#pragma unroll
    for (int j = 0; j < 4; ++j) {
      bf16x8 fb = *(const bf16x8*)(bp + j*16*BKP);
      if constexpr (SPLIT) {
        bf16x8 fbl = *(const bf16x8*)(bp + BBUF + j*16*BKP);
#pragma unroll
        for (int i = 0; i < 4; ++i) {
          acc[i][j] = __builtin_amdgcn_mfma_f32_16x16x32_bf16(fa[i],  fbl, acc[i][j], 0, 0, 0);
          acc[i][j] = __builtin_amdgcn_mfma_f32_16x16x32_bf16(fal[i], fb,  acc[i][j], 0, 0, 0);
          acc[i][j] = __builtin_amdgcn_mfma_f32_16x16x32_bf16(fa[i],  fb,  acc[i][j], 0, 0, 0);
        }
      } else {
#pragma unroll
        for (int i = 0; i < 4; ++i)
          acc[i][j] = __builtin_amdgcn_mfma_f32_16x16x32_bf16(fa[i], fb, acc[i][j], 0, 0, 0);
      }
    }
  }

  // epilogue: C/D layout col=lane&15, row=(lane>>4)*4+reg
#pragma unroll
  for (int i = 0; i < 4; ++i) {
#pragma unroll
    for (int rg = 0; rg < 4; ++rg) {
      int lrow = wm*64 + i*16 + lq*4 + rg;
      int gr = m0 + lrow;
      if (gr < mcount) {
        long crow = coff + (long)(rowbase + gr)*ldc;
#pragma unroll
        for (int j = 0; j < 4; ++j) {
          int col = n0 + wn*64 + j*16 + lr;
          float val = acc[i][j][rg];
          if constexpr (RESID) val += Rres[(long)gr*ldc + col];
          C[crow + col] = val;
        }
      }
    }
  }
}

template<typename OT>
__global__ void rmsnorm_kernel(const float* __restrict__ x, const float* __restrict__ w,
                               OT* __restrict__ out) {
  const int row = blockIdx.x;
  const float* xr = x + (long)row * 2048;
  float ss = 0.f;
  for (int d = threadIdx.x; d < 2048; d += 256) { float v = xr[d]; ss += v*v; }
  __shared__ float red[4];
  int lane = threadIdx.x & 63, wave = threadIdx.x >> 6;
#pragma unroll
  for (int off = 32; off; off >>= 1) ss += __shfl_down(ss, off, 64);
  if (lane == 0) red[wave] = ss;
  __syncthreads();
  float tot = red[0] + red[1] + red[2] + red[3];
  float rs = rsqrtf(tot * (1.f/2048.f) + 1e-6f);
  OT* orow = out + (long)row * 2048;
  for (int d = threadIdx.x; d < 2048; d += 256) orow[d] = (OT)(xr[d]*rs*w[d]);
}

// in-place fp32 RoPE on q and k
__global__ void rope_kernel(float* __restrict__ q, float* __restrict__ k) {
  int tid = blockIdx.x*256 + threadIdx.x;   // T*H*64 = 1,048,576 threads
  int i = tid & 63;
  int t = tid >> 10;
  int s = t & 511;
  long base = ((long)(tid >> 6)) * 128;
  float inv = 1.f / powf(10000.f, (float)i * (1.f/64.f));
  float ang = (float)s * inv;
  float c = cosf(ang), sn = sinf(ang);
  float q1 = q[base+i], q2 = q[base+64+i];
  q[base+i]    = q1*c - q2*sn;
  q[base+64+i] = q2*c + q1*sn;
  float k1 = k[base+i], k2 = k[base+64+i];
  k[base+i]    = k1*c - k2*sn;
  k[base+64+i] = k2*c + k1*sn;
}

// causal softmax, fp32 in-place (scores -> P)
__global__ void softmax_kernel(float* __restrict__ sc) {
  int r = blockIdx.x & 511;
  long bh = blockIdx.x >> 9;
  const float scale = 0.08838834764831845f;   // 1/sqrt(128)
  long base = (bh*512 + r)*512;
  int c0 = threadIdx.x, c1 = threadIdx.x + 256;
  float v0 = (c0 <= r) ? sc[base+c0]*scale : -3.0e38f;
  float v1 = (c1 <= r) ? sc[base+c1]*scale : -3.0e38f;
  float m = fmaxf(v0, v1);
  __shared__ float red[4];
  int lane = threadIdx.x & 63, wave = threadIdx.x >> 6;
#pragma unroll
  for (int off = 32; off; off >>= 1) m = fmaxf(m, __shfl_xor(m, off, 64));
  if (lane == 0) red[wave] = m;
  __syncthreads();
  m = fmaxf(fmaxf(red[0], red[1]), fmaxf(red[2], red[3]));
  __syncthreads();
  float e0 = (c0 <= r) ? expf(v0 - m) : 0.f;
  float e1 = (c1 <= r) ? expf(v1 - m) : 0.f;
  float s = e0 + e1;
#pragma unroll
  for (int off = 32; off; off >>= 1) s += __shfl_xor(s, off, 64);
  if (lane == 0) red[wave] = s;
  __syncthreads();
  s = red[0] + red[1] + red[2] + red[3];
  float inv = 1.f / s;
  sc[base+c0] = e0*inv;
  sc[base+c1] = e1*inv;
}

__global__ void zero8_kernel(int* c) { if (threadIdx.x < 8) c[threadIdx.x] = 0; }

// routing in fp32 from h2 (inline rmsnorm) — h2 is now fp32-accurate via split GEMMs
__global__ void routing_kernel(const float* __restrict__ h2, const float* __restrict__ ln2w,
                               const float* __restrict__ gw, const float* __restrict__ gb,
                               int* __restrict__ eidx, float* __restrict__ ew,
                               int* __restrict__ counts) {
  int t = blockIdx.x;
  const float* xr = h2 + (long)t*2048;
  int lane = threadIdx.x & 63, wave = threadIdx.x >> 6;
  float ss = 0.f;
  for (int d = threadIdx.x; d < 2048; d += 256) { float v = xr[d]; ss += v*v; }
  __shared__ float red[4];
#pragma unroll
  for (int off = 32; off; off >>= 1) ss += __shfl_down(ss, off, 64);
  if (lane == 0) red[wave] = ss;
  __syncthreads();
  float rs = rsqrtf((red[0]+red[1]+red[2]+red[3]) * (1.f/2048.f) + 1e-6f);
  __shared__ float lg[8];
  for (int e = wave; e < 8; e += 4) {
    const float* wr = gw + (long)e*2048;
    float acc = 0.f;
    for (int d = lane; d < 2048; d += 64) acc += (xr[d]*rs*ln2w[d]) * wr[d];
#pragma unroll
    for (int off = 32; off; off >>= 1) acc += __shfl_down(acc, off, 64);
    if (lane == 0) lg[e] = acc;
  }
  __syncthreads();
  if (threadIdx.x == 0) {
    float sg[8], sc[8];
#pragma unroll
    for (int e = 0; e < 8; ++e) { sg[e] = 1.f/(1.f+expf(-lg[e])); sc[e] = sg[e] + gb[e]; }
    float gs[2];
#pragma unroll
    for (int g = 0; g < 2; ++g) {
      float m1 = -3e38f, m2 = -3e38f;
#pragma unroll
      for (int j = 0; j < 4; ++j) {
        float v = sc[4*g+j];
        if (v > m1) { m2 = m1; m1 = v; } else if (v > m2) m2 = v;
      }
      gs[g] = m1 + m2;
    }
    int b4 = (gs[1] > gs[0]) ? 4 : 0;
    int i1 = 0; float v1 = -3e38f;
#pragma unroll
    for (int j = 0; j < 4; ++j) if (sc[b4+j] > v1) { v1 = sc[b4+j]; i1 = j; }
    int i2 = -1; float v2 = -3e38f;
#pragma unroll
    for (int j = 0; j < 4; ++j) if (j != i1 && sc[b4+j] > v2) { v2 = sc[b4+j]; i2 = j; }
    float w1 = sg[b4+i1], w2 = sg[b4+i2], s = w1 + w2;
    eidx[t*2] = b4+i1; eidx[t*2+1] = b4+i2;
    ew[t*2] = w1/s;    ew[t*2+1] = w2/s;
    atomicAdd(&counts[b4+i1], 1); atomicAdd(&counts[b4+i2], 1);
  }
}

__global__ void scan_kernel(const int* __restrict__ counts, int* __restrict__ offsets,
                            int* __restrict__ cursors) {
  if (threadIdx.x == 0 && blockIdx.x == 0) {
    int s = 0;
    for (int e = 0; e < 8; ++e) { offsets[e] = s; s += counts[e]; cursors[e] = 0; }
    offsets[8] = s;
  }
}

__global__ void scatter_kernel(const int* __restrict__ eidx, const int* __restrict__ offsets,
                               int* __restrict__ cursors, int* __restrict__ list,
                               int* __restrict__ slot) {
  int t = blockIdx.x*256 + threadIdx.x;
  if (t < 1024) {
#pragma unroll
    for (int kk = 0; kk < 2; ++kk) {
      int e = eidx[t*2+kk];
      int pos = atomicAdd(&cursors[e], 1);
      int g = offsets[e] + pos;
      list[g] = t;
      slot[t*2+kk] = g;
    }
  }
}

__global__ void silumul_kernel(const float* __restrict__ g, const float* __restrict__ u,
                               __bf16* __restrict__ o, int n) {
  int i = blockIdx.x*256 + threadIdx.x;
  if (i < n) {
    float gv = g[i];
    float s = gv / (1.f + expf(-gv));
    o[i] = (__bf16)(s * u[i]);
  }
}

__global__ void combine_kernel(const float* __restrict__ h2, const float* __restrict__ y,
                               const float* __restrict__ sdown, const int* __restrict__ slot,
                               const float* __restrict__ ew, float* __restrict__ out) {
  int i = blockIdx.x*256 + threadIdx.x;   // < 1024*2048
  int t = i >> 11;
  int d = i & 2047;
  float rv = ew[t*2]   * y[(long)slot[t*2]  *2048 + d]
           + ew[t*2+1] * y[(long)slot[t*2+1]*2048 + d];
  out[i] = h2[i] + sdown[i] + 2.5f * rv;
}

extern "C" void kernel_launch(void* const* d_in, const int* in_sizes, int n_in,
                              void* d_out, int out_size, void* d_ws, size_t ws_size,
                              hipStream_t stream) {
  const float* hid  = (const float*)d_in[0];
  const float* ln1  = (const float*)d_in[1];
  const float* ln2  = (const float*)d_in[2];
  const float* wq   = (const float*)d_in[3];
  const float* wk   = (const float*)d_in[4];
  const float* wv   = (const float*)d_in[5];
  const float* wo   = (const float*)d_in[6];
  const float* gw   = (const float*)d_in[7];
  const float* gb   = (const float*)d_in[8];
  const float* wgat = (const float*)d_in[9];
  const float* wup  = (const float*)d_in[10];
  const float* wdn  = (const float*)d_in[11];
  const float* swg  = (const float*)d_in[12];
  const float* swu  = (const float*)d_in[13];
  const float* swd  = (const float*)d_in[14];
  float* out = (float*)d_out;
  char* ws = (char*)d_ws;

  float*  xn1 = (float*)(ws + oXN1);
  float*  qf  = (float*)(ws + oQF);
  float*  kf  = (float*)(ws + oKF);
  float*  vf  = (float*)(ws + oVF);
  float*  scf = (float*)(ws + oSC);
  float*  att = (float*)(ws + oATT);
  float*  h2  = (float*)(ws + oH2);
  __bf16* xb2 = (__bf16*)(ws + oXB2);
  float*  gbuf= (float*)(ws + oG);
  float*  ubuf= (float*)(ws + oU);
  __bf16* hb  = (__bf16*)(ws + oHB);
  float*  ybuf= (float*)(ws + oY);
  float*  sgb = (float*)(ws + oSG);
  float*  sub = (float*)(ws + oSU);
  __bf16* shb = (__bf16*)(ws + oSH);
  float*  sdb = (float*)(ws + oSD);
  int*   eidx = (int*)(ws + oEIDX);
  float* ew   = (float*)(ws + oEW);
  int*   slot = (int*)(ws + oSLOT);
  int*   list = (int*)(ws + oLIST);
  int*   cnt  = (int*)(ws + oCNT);
  int*   offs = (int*)(ws + oOFF);
  int*   curs = (int*)(ws + oCUR);

  // 1. rmsnorm1 -> f32 (precision path)
  rmsnorm_kernel<float><<<1024, 256, 0, stream>>>(hid, ln1, xn1);

  // 2. QKV projections (split-bf16, fp32-accurate)
  gemm_kernel<0, true, float, float, false, false, false, false><<<dim3(16,8,1), 256, 0, stream>>>(
      xn1, wq, qf, nullptr, 1024, 2048, 2048, 2048, 2048, 2048,
      1, 0, 0, 0, 0, 0, 0, nullptr, nullptr, nullptr);
  gemm_kernel<0, true, float, float, false, false, false, false><<<dim3(16,8,1), 256, 0, stream>>>(
      xn1, wk, kf, nullptr, 1024, 2048, 2048, 2048, 2048, 2048,
      1, 0, 0, 0, 0, 0, 0, nullptr, nullptr, nullptr);
  gemm_kernel<0, true, float, float, false, false, false, false><<<dim3(16,8,1), 256, 0, stream>>>(
      xn1, wv, vf, nullptr, 1024, 2048, 2048, 2048, 2048, 2048,
      1, 0, 0, 0, 0, 0, 0, nullptr, nullptr, nullptr);

  // 3. RoPE in fp32, in place
  rope_kernel<<<4096, 256, 0, stream>>>(qf, kf);

  // 4. scores = Q @ K^T (split, NT, causal tile-skip), batched over 32 (b,h)
  gemm_kernel<0, true, float, float, true, false, true, false><<<dim3(4,4,32), 256, 0, stream>>>(
      qf, kf, scf, nullptr, 512, 512, 128, 2048, 2048, 512,
      16, (long)512*2048, 128L, (long)512*2048, 128L, (long)16*512*512, (long)512*512,
      nullptr, nullptr, nullptr);

  // 5. causal softmax fp32 in-place (scores -> P)
  softmax_kernel<<<16384, 256, 0, stream>>>(scf);

  // 6. attn = P @ V (split, K-early-stop via causality)
  gemm_kernel<0, true, float, float, false, false, false, true><<<dim3(1,4,32), 256, 0, stream>>>(
      scf, vf, att, nullptr, 512, 128, 512, 512, 2048, 2048,
      16, (long)16*512*512, (long)512*512, (long)512*2048, 128L, (long)512*2048, 128L,
      nullptr, nullptr, nullptr);

  // 7. h2 = hidden + attn @ wo (split)
  gemm_kernel<0, true, float, float, false, true, false, false><<<dim3(16,8,1), 256, 0, stream>>>(
      att, wo, h2, hid, 1024, 2048, 2048, 2048, 2048, 2048,
      1, 0, 0, 0, 0, 0, 0, nullptr, nullptr, nullptr);

  // 8. rmsnorm2 -> bf16 (MoE fast path input)
  rmsnorm_kernel<__bf16><<<1024, 256, 0, stream>>>(h2, ln2, xb2);

  // 9-12. routing (fp32, from fp32-accurate h2)
  zero8_kernel<<<1, 64, 0, stream>>>(cnt);
  routing_kernel<<<1024, 256, 0, stream>>>(h2, ln2, gw, gb, eidx, ew, cnt);
  scan_kernel<<<1, 64, 0, stream>>>(cnt, offs, curs);
  scatter_kernel<<<4, 256, 0, stream>>>(eidx, offs, curs, list, slot);

  // 13-16. routed experts (gathered rows, fast bf16)
  gemm_kernel<1, false, __bf16, float, false, false, false, false><<<dim3(8,8,8), 256, 0, stream>>>(
      xb2, wgat, gbuf, nullptr, 1024, 1024, 2048, 2048, 1024, 1024,
      1, 0, 0, (long)2048*1024, 0, 0, 0, cnt, offs, list);
  gemm_kernel<1, false, __bf16, float, false, false, false, false><<<dim3(8,8,8), 256, 0, stream>>>(
      xb2, wup, ubuf, nullptr, 1024, 1024, 2048, 2048, 1024, 1024,
      1, 0, 0, (long)2048*1024, 0, 0, 0, cnt, offs, list);
  silumul_kernel<<<8192, 256, 0, stream>>>(gbuf, ubuf, hb, 2048*1024);
  gemm_kernel<2, false, __bf16, float, false, false, false, false><<<dim3(16,8,8), 256, 0, stream>>>(
      hb, wdn, ybuf, nullptr, 1024, 2048, 1024, 1024, 2048, 2048,
      1, 0, 0, (long)1024*2048, 0, 0, 0, cnt, offs, nullptr);

  // 17-20. shared expert (fast bf16)
  gemm_kernel<0, false, __bf16, float, false, false, false, false><<<dim3(8,8,1), 256, 0, stream>>>(
      xb2, swg, sgb, nullptr, 1024, 1024, 2048, 2048, 1024, 1024,
      1, 0, 0, 0, 0, 0, 0, nullptr, nullptr, nullptr);
  gemm_kernel<0, false, __bf16, float, false, false, false, false><<<dim3(8,8,1), 256, 0, stream>>>(
      xb2, swu, sub, nullptr, 1024, 1024, 2048, 2048, 1024, 1024,
      1, 0, 0, 0, 0, 0, 0, nullptr, nullptr, nullptr);
  silumul_kernel<<<4096, 256, 0, stream>>>(sgb, sub, shb, 1024*1024);
  gemm_kernel<0, false, __bf16, float, false, false, false, false><<<dim3(16,8,1), 256, 0, stream>>>(
      shb, swd, sdb, nullptr, 1024, 2048, 1024, 1024, 2048, 2048,
      1, 0, 0, 0, 0, 0, 0, nullptr, nullptr, nullptr);

  // 21. combine: out = h2 + shared + 2.5*(w0*y[slot0] + w1*y[slot1])
  combine_kernel<<<8192, 256, 0, stream>>>(h2, ybuf, sdb, slot, ew, out);
}

// Round 3
// 1156.770 us; speedup vs baseline: 2.0795x; 2.0795x over previous
//
#include <hip/hip_runtime.h>

typedef __bf16 bf16x4 __attribute__((ext_vector_type(4)));
typedef __bf16 bf16x8 __attribute__((ext_vector_type(8)));
typedef float  f32x4  __attribute__((ext_vector_type(4)));

#define THREADS 256
constexpr int BM = 128, BN = 128, BK = 32, BKP = 40;

// ---- workspace layout (bytes), total 160 MB ----
constexpr size_t MB = 1024*1024;
// persistent across whole launch
constexpr size_t oH2    = 0;            // f32 [1024,2048] 8MB
constexpr size_t oXB2   = 8*MB;         // bf16 [1024,2048] 4MB
constexpr size_t oRT    = 12*MB;        // routing scratch
// attention phase
constexpr size_t oWQKVT = 16*MB;        // f32 [6144,2048] 48MB (dead after QKV gemm)
constexpr size_t oWOT   = 64*MB;        // f32 [2048,2048] 16MB (dead after wo gemm)
constexpr size_t oXN1   = 80*MB;        // f32 [1024,2048] 8MB (dead after QKV gemm)
constexpr size_t oQKV   = 88*MB;        // f32 [1024,6144] 24MB (dead after PV/VT)
constexpr size_t oSC    = 112*MB;       // f32 [32,512,512] 32MB (dead after PV)
constexpr size_t oVT    = 144*MB;       // f32 [32,128,512] 8MB (dead after PV)
constexpr size_t oATT   = 152*MB;       // f32 [1024,2048] 8MB (dead after wo gemm)
// MoE phase (overlays dead attention regions)
constexpr size_t oWGUT  = 16*MB;        // bf16 [8,2048,2048] 64MB
constexpr size_t oWDT   = 80*MB;        // bf16 [8,2048,1024] 32MB
constexpr size_t oSGUT  = 112*MB;       // bf16 [2048,2048] 8MB
constexpr size_t oSDT   = 120*MB;       // bf16 [2048,1024] 4MB
constexpr size_t oGU    = 124*MB;       // f32 [2048,2048] 16MB
constexpr size_t oHB    = 140*MB;       // bf16 [2048,1024] 4MB
constexpr size_t oY     = 144*MB;       // f32 [2048,2048] 16MB
constexpr size_t oSGU   = 16*MB;        // f32 [1024,2048] 8MB (wgut dead after routed-gu gemm)
constexpr size_t oSHB   = 24*MB;        // bf16 [1024,1024] 2MB
constexpr size_t oSDB   = 26*MB;        // f32 [1024,2048] 8MB
// routing arrays inside oRT
constexpr size_t oEIDX = oRT;
constexpr size_t oEW   = oRT + 8192;
constexpr size_t oSLOT = oRT + 16384;
constexpr size_t oLIST = oRT + 24576;
constexpr size_t oCNT  = oRT + 32768;
constexpr size_t oOFF  = oRT + 33024;
constexpr size_t oCUR  = oRT + 33280;

// ---- 64x64 LDS tile transpose: f32 [rows,cols] -> OUT [cols,rows] ----
template<typename OUT>
__global__ void transpose_kernel(const float* __restrict__ in, OUT* __restrict__ out,
                                 int ldin, int ldout, int zlo,
                                 long inBH, long inBL, long outB) {
  __shared__ float tile[64][65];
  int z = blockIdx.z;
  const float* inp = in + (long)(z / zlo) * inBH + (long)(z % zlo) * inBL;
  OUT* outp = out + (long)z * outB;
  int r0 = blockIdx.y * 64, c0 = blockIdx.x * 64;
  int tid = threadIdx.x;
#pragma unroll
  for (int i = 0; i < 4; ++i) {
    int lin = tid + i * 256;
    int r = lin >> 4, c4 = (lin & 15) << 2;
    f32x4 v = *(const f32x4*)(inp + (long)(r0 + r) * ldin + c0 + c4);
    tile[r][c4] = v[0]; tile[r][c4+1] = v[1]; tile[r][c4+2] = v[2]; tile[r][c4+3] = v[3];
  }
  __syncthreads();
#pragma unroll
  for (int i = 0; i < 4; ++i) {
    int lin = tid + i * 256;
    int oR = lin >> 4, oC4 = (lin & 15) << 2;
    OUT w[4];
#pragma unroll
    for (int j = 0; j < 4; ++j) w[j] = (OUT)tile[oC4 + j][oR];
    *(OUT*)0; // placeholder avoided below
    OUT* dst = outp + (long)(c0 + oR) * ldout + r0 + oC4;
    dst[0] = w[0]; dst[1] = w[1]; dst[2] = w[2]; dst[3] = w[3];
  }
}

// MODE 0: batched strided; MODE 1: gathered A rows; MODE 2: dense A rows at offsets
// SPLIT: A,B are f32, decomposed hi+lo bf16 on the fly, 3-term MFMA (fp32-like precision)
// !SPLIT: A,B are bf16. B is ALWAYS pre-transposed [N,K] (TRANSB).
template<int MODE, bool SPLIT, bool RESID, bool CAUSAL, bool KTRI>
__global__ __launch_bounds__(256, 2)
void gemm_kernel(const void* __restrict__ Av, const void* __restrict__ Bv, float* __restrict__ C,
                 const float* __restrict__ Rres,
                 int M, int N, int K, int lda, int ldb, int ldc,
                 int zlo, long aHi, long aLo, long bHi, long bLo, long cHi, long cLo,
                 const int* __restrict__ counts, const int* __restrict__ offsets,
                 const int* __restrict__ gather) {
  const int n0 = blockIdx.x * BN;
  const int m0 = blockIdx.y * BM;
  const int z  = blockIdx.z;
  if (CAUSAL && n0 > m0) return;   // fully-masked score tile

  const float*  Af = (const float*)Av;
  const __bf16* Ah = (const __bf16*)Av;
  const float*  Bf = (const float*)Bv;
  const __bf16* Bh = (const __bf16*)Bv;

  int mcount; int rowbase = 0;
  long aoff = 0, boff = 0, coff = 0;
  if constexpr (MODE == 0) {
    mcount = M;
    int zh = z / zlo, zl = z % zlo;
    aoff = (long)zh*aHi + (long)zl*aLo;
    boff = (long)zh*bHi + (long)zl*bLo;
    coff = (long)zh*cHi + (long)zl*cLo;
  } else {
    mcount = counts[z];
    rowbase = offsets[z];
    if (m0 >= mcount) return;
    boff = (long)z*bHi;
  }

  constexpr int ABUF = BM*BKP;
  constexpr int BBUF = BN*BKP;
  __shared__ __align__(16) __bf16 As[(SPLIT?2:1)*ABUF];
  __shared__ __align__(16) __bf16 Bs[(SPLIT?2:1)*BBUF];

  const int tid = threadIdx.x;
  const int lane = tid & 63, wave = tid >> 6;
  const int wm = wave >> 1, wn = wave & 1;
  const int lq = lane >> 4, lr = lane & 15;

  int kend = K;
  if (KTRI) { int ke = m0 + BM; kend = ke < K ? ke : K; }

  f32x4 acc[4][4] = {};

  for (int k0 = 0; k0 < kend; k0 += BK) {
    if (k0) __syncthreads();
    // stage A tile [BM][BK] (K-contig vec4 loads, conflict-free LDS writes)
#pragma unroll
    for (int it = 0; it < 4; ++it) {
      int lin = tid + it*THREADS;
      int row = lin >> 3;
      int c4  = (lin & 7) << 2;
      int gr  = m0 + row;
      bf16x4 hi, lo;
      hi[0]=hi[1]=hi[2]=hi[3]=(__bf16)0.0f;
      lo[0]=lo[1]=lo[2]=lo[3]=(__bf16)0.0f;
      if (gr < mcount) {
        long arow;
        if constexpr (MODE == 1) arow = gather[rowbase + gr];
        else if constexpr (MODE == 2) arow = rowbase + gr;
        else arow = gr;
        if constexpr (SPLIT) {
          f32x4 v = *(const f32x4*)(Af + aoff + arow*(long)lda + k0 + c4);
#pragma unroll
          for (int j = 0; j < 4; ++j) {
            hi[j] = (__bf16)v[j];
            lo[j] = (__bf16)(v[j] - (float)hi[j]);
          }
        } else {
          hi = *(const bf16x4*)(Ah + aoff + arow*(long)lda + k0 + c4);
        }
      }
      *(bf16x4*)(As + row*BKP + c4) = hi;
      if constexpr (SPLIT) *(bf16x4*)(As + ABUF + row*BKP + c4) = lo;
    }
    // stage B tile [BN][BK] from pre-transposed B (K-contig)
#pragma unroll
    for (int it = 0; it < 4; ++it) {
      int lin = tid + it*THREADS;
      int row = lin >> 3;
      int c4  = (lin & 7) << 2;
      if constexpr (SPLIT) {
        f32x4 v = *(const f32x4*)(Bf + boff + (long)(n0+row)*ldb + k0 + c4);
        bf16x4 hi, lo;
#pragma unroll
        for (int j = 0; j < 4; ++j) {
          hi[j] = (__bf16)v[j];
          lo[j] = (__bf16)(v[j] - (float)hi[j]);
        }
        *(bf16x4*)(Bs + row*BKP + c4) = hi;
        *(bf16x4*)(Bs + BBUF + row*BKP + c4) = lo;
      } else {
        *(bf16x4*)(Bs + row*BKP + c4) =
            *(const bf16x4*)(Bh + boff + (long)(n0+row)*ldb + k0 + c4);
      }
    }
    __syncthreads();

    bf16x8 fa[4], fal[4];
    const __bf16* ap = As + (wm*64 + lr)*BKP + lq*8;
    const __bf16* bp = Bs + (wn*64 + lr)*BKP + lq*8;
#pragma unroll
    for (int i = 0; i < 4; ++i) {
      fa[i] = *(const bf16x8*)(ap + i*16*BKP);
      if constexpr (SPLIT) fal[i] = *(const bf16x8*)(ap + ABUF + i*16*BKP);
    }
#pragma unroll
    for (int j = 0; j < 4; ++j) {
      bf16x8 fb = *(const bf16x8*)(bp + j*16*BKP);
      if constexpr (SPLIT) {
        bf16x8 fbl = *(const bf16x8*)(bp + BBUF + j*16*BKP);
#pragma unroll
        for (int i = 0; i < 4; ++i) {
          acc[i][j] = __builtin_amdgcn_mfma_f32_16x16x32_bf16(fa[i],  fbl, acc[i][j], 0, 0, 0);
          acc[i][j] = __builtin_amdgcn_mfma_f32_16x16x32_bf16(fal[i], fb,  acc[i][j], 0, 0, 0);
          acc[i][j] = __builtin_amdgcn_mfma_f32_16x16x32_bf16(fa[i],  fb,  acc[i][j], 0, 0, 0);
        }
      } else {
#pragma unroll
        for (int i = 0; i < 4; ++i)
          acc[i][j] = __builtin_amdgcn_mfma_f32_16x16x32_bf16(fa[i], fb, acc[i][j], 0, 0, 0);
      }
    }
  }

  // epilogue: C/D layout col=lane&15, row=(lane>>4)*4+reg
#pragma unroll
  for (int i = 0; i < 4; ++i) {
#pragma unroll
    for (int rg = 0; rg < 4; ++rg) {
      int lrow = wm*64 + i*16 + lq*4 + rg;
      int gr = m0 + lrow;
      if (gr < mcount) {
        long crow = coff + (long)(rowbase + gr)*ldc;
#pragma unroll
        for (int j = 0; j < 4; ++j) {
          int col = n0 + wn*64 + j*16 + lr;
          float val = acc[i][j][rg];
          if constexpr (RESID) val += Rres[(long)gr*ldc + col];
          C[crow + col] = val;
        }
      }
    }
  }
}

template<typename OT>
__global__ void rmsnorm_kernel(const float* __restrict__ x, const float* __restrict__ w,
                               OT* __restrict__ out) {
  const int row = blockIdx.x;
  const float* xr = x + (long)row * 2048;
  float ss = 0.f;
  for (int d = threadIdx.x; d < 2048; d += 256) { float v = xr[d]; ss += v*v; }
  __shared__ float red[4];
  int lane = threadIdx.x & 63, wave = threadIdx.x >> 6;
#pragma unroll
  for (int off = 32; off; off >>= 1) ss += __shfl_down(ss, off, 64);
  if (lane == 0) red[wave] = ss;
  __syncthreads();
  float tot = red[0] + red[1] + red[2] + red[3];
  float rs = rsqrtf(tot * (1.f/2048.f) + 1e-6f);
  OT* orow = out + (long)row * 2048;
  for (int d = threadIdx.x; d < 2048; d += 256) orow[d] = (OT)(xr[d]*rs*w[d]);
}

// in-place fp32 RoPE on q,k inside qkv [1024][6144] (q at col 0, k at col 2048)
__global__ void rope_kernel(float* __restrict__ qkv) {
  int tid = blockIdx.x*256 + threadIdx.x;   // 1024*16*64 threads
  int i = tid & 63;
  int th = tid >> 6;
  int h = th & 15;
  int t = th >> 4;
  int s = t & 511;
  long base = (long)t*6144 + h*128;
  float inv = 1.f / powf(10000.f, (float)i * (1.f/64.f));
  float ang = (float)s * inv;
  float c = cosf(ang), sn = sinf(ang);
  float q1 = qkv[base+i], q2 = qkv[base+64+i];
  qkv[base+i]    = q1*c - q2*sn;
  qkv[base+64+i] = q2*c + q1*sn;
  float k1 = qkv[base+2048+i], k2 = qkv[base+2048+64+i];
  qkv[base+2048+i]    = k1*c - k2*sn;
  qkv[base+2048+64+i] = k2*c + k1*sn;
}

// causal softmax, fp32 in-place (scores -> P)
__global__ void softmax_kernel(float* __restrict__ sc) {
  int r = blockIdx.x & 511;
  long bh = blockIdx.x >> 9;
  const float scale = 0.08838834764831845f;   // 1/sqrt(128)
  long base = (bh*512 + r)*512;
  int c0 = threadIdx.x, c1 = threadIdx.x + 256;
  float v0 = (c0 <= r) ? sc[base+c0]*scale : -3.0e38f;
  float v1 = (c1 <= r) ? sc[base+c1]*scale : -3.0e38f;
  float m = fmaxf(v0, v1);
  __shared__ float red[4];
  int lane = threadIdx.x & 63, wave = threadIdx.x >> 6;
#pragma unroll
  for (int off = 32; off; off >>= 1) m = fmaxf(m, __shfl_xor(m, off, 64));
  if (lane == 0) red[wave] = m;
  __syncthreads();
  m = fmaxf(fmaxf(red[0], red[1]), fmaxf(red[2], red[3]));
  __syncthreads();
  float e0 = (c0 <= r) ? expf(v0 - m) : 0.f;
  float e1 = (c1 <= r) ? expf(v1 - m) : 0.f;
  float s = e0 + e1;
#pragma unroll
  for (int off = 32; off; off >>= 1) s += __shfl_xor(s, off, 64);
  if (lane == 0) red[wave] = s;
  __syncthreads();
  s = red[0] + red[1] + red[2] + red[3];
  float inv = 1.f / s;
  sc[base+c0] = e0*inv;
  sc[base+c1] = e1*inv;
}

__global__ void zero8_kernel(int* c) { if (threadIdx.x < 8) c[threadIdx.x] = 0; }

__global__ void routing_kernel(const float* __restrict__ h2, const float* __restrict__ ln2w,
                               const float* __restrict__ gw, const float* __restrict__ gb,
                               int* __restrict__ eidx, float* __restrict__ ew,
                               int* __restrict__ counts) {
  int t = blockIdx.x;
  const float* xr = h2 + (long)t*2048;
  int lane = threadIdx.x & 63, wave = threadIdx.x >> 6;
  float ss = 0.f;
  for (int d = threadIdx.x; d < 2048; d += 256) { float v = xr[d]; ss += v*v; }
  __shared__ float red[4];
#pragma unroll
  for (int off = 32; off; off >>= 1) ss += __shfl_down(ss, off, 64);
  if (lane == 0) red[wave] = ss;
  __syncthreads();
  float rs = rsqrtf((red[0]+red[1]+red[2]+red[3]) * (1.f/2048.f) + 1e-6f);
  __shared__ float lg[8];
  for (int e = wave; e < 8; e += 4) {
    const float* wr = gw + (long)e*2048;
    float acc = 0.f;
    for (int d = lane; d < 2048; d += 64) acc += (xr[d]*rs*ln2w[d]) * wr[d];
#pragma unroll
    for (int off = 32; off; off >>= 1) acc += __shfl_down(acc, off, 64);
    if (lane == 0) lg[e] = acc;
  }
  __syncthreads();
  if (threadIdx.x == 0) {
    float sg[8], sc[8];
#pragma unroll
    for (int e = 0; e < 8; ++e) { sg[e] = 1.f/(1.f+expf(-lg[e])); sc[e] = sg[e] + gb[e]; }
    float gs[2];
#pragma unroll
    for (int g = 0; g < 2; ++g) {
      float m1 = -3e38f, m2 = -3e38f;
#pragma unroll
      for (int j = 0; j < 4; ++j) {
        float v = sc[4*g+j];
        if (v > m1) { m2 = m1; m1 = v; } else if (v > m2) m2 = v;
      }
      gs[g] = m1 + m2;
    }
    int b4 = (gs[1] > gs[0]) ? 4 : 0;
    int i1 = 0; float v1 = -3e38f;
#pragma unroll
    for (int j = 0; j < 4; ++j) if (sc[b4+j] > v1) { v1 = sc[b4+j]; i1 = j; }
    int i2 = -1; float v2 = -3e38f;
#pragma unroll
    for (int j = 0; j < 4; ++j) if (j != i1 && sc[b4+j] > v2) { v2 = sc[b4+j]; i2 = j; }
    float w1 = sg[b4+i1], w2 = sg[b4+i2], s = w1 + w2;
    eidx[t*2] = b4+i1; eidx[t*2+1] = b4+i2;
    ew[t*2] = w1/s;    ew[t*2+1] = w2/s;
    atomicAdd(&counts[b4+i1], 1); atomicAdd(&counts[b4+i2], 1);
  }
}

__global__ void scan_kernel(const int* __restrict__ counts, int* __restrict__ offsets,
                            int* __restrict__ cursors) {
  if (threadIdx.x == 0 && blockIdx.x == 0) {
    int s = 0;
    for (int e = 0; e < 8; ++e) { offsets[e] = s; s += counts[e]; cursors[e] = 0; }
    offsets[8] = s;
  }
}

__global__ void scatter_kernel(const int* __restrict__ eidx, const int* __restrict__ offsets,
                               int* __restrict__ cursors, int* __restrict__ list,
                               int* __restrict__ slot) {
  int t = blockIdx.x*256 + threadIdx.x;
  if (t < 1024) {
#pragma unroll
    for (int kk = 0; kk < 2; ++kk) {
      int e = eidx[t*2+kk];
      int pos = atomicAdd(&cursors[e], 1);
      int g = offsets[e] + pos;
      list[g] = t;
      slot[t*2+kk] = g;
    }
  }
}

// fused gate|up layout: gu[s][0:1024]=gate, gu[s][1024:2048]=up -> hb[s][0:1024]
__global__ void silumul_kernel(const float* __restrict__ gu, __bf16* __restrict__ o, int n) {
  int i = blockIdx.x*256 + threadIdx.x;
  if (i < n) {
    int s = i >> 10, j = i & 1023;
    float gv = gu[(long)s*2048 + j];
    float uv = gu[(long)s*2048 + 1024 + j];
    float sg = gv / (1.f + expf(-gv));
    o[i] = (__bf16)(sg * uv);
  }
}

__global__ void combine_kernel(const float* __restrict__ h2, const float* __restrict__ y,
                               const float* __restrict__ sdown, const int* __restrict__ slot,
                               const float* __restrict__ ew, float* __restrict__ out) {
  int i = blockIdx.x*256 + threadIdx.x;   // < 1024*2048
  int t = i >> 11;
  int d = i & 2047;
  float rv = ew[t*2]   * y[(long)slot[t*2]  *2048 + d]
           + ew[t*2+1] * y[(long)slot[t*2+1]*2048 + d];
  out[i] = h2[i] + sdown[i] + 2.5f * rv;
}

extern "C" void kernel_launch(void* const* d_in, const int* in_sizes, int n_in,
                              void* d_out, int out_size, void* d_ws, size_t ws_size,
                              hipStream_t stream) {
  const float* hid  = (const float*)d_in[0];
  const float* ln1  = (const float*)d_in[1];
  const float* ln2  = (const float*)d_in[2];
  const float* wq   = (const float*)d_in[3];
  const float* wk   = (const float*)d_in[4];
  const float* wv   = (const float*)d_in[5];
  const float* wo   = (const float*)d_in[6];
  const float* gw   = (const float*)d_in[7];
  const float* gb   = (const float*)d_in[8];
  const float* wgat = (const float*)d_in[9];
  const float* wup  = (const float*)d_in[10];
  const float* wdn  = (const float*)d_in[11];
  const float* swg  = (const float*)d_in[12];
  const float* swu  = (const float*)d_in[13];
  const float* swd  = (const float*)d_in[14];
  float* out = (float*)d_out;
  char* ws = (char*)d_ws;

  float*  h2   = (float*)(ws + oH2);
  __bf16* xb2  = (__bf16*)(ws + oXB2);
  float*  wqkvT= (float*)(ws + oWQKVT);
  float*  woT  = (float*)(ws + oWOT);
  float*  xn1  = (float*)(ws + oXN1);
  float*  qkv  = (float*)(ws + oQKV);
  float*  scf  = (float*)(ws + oSC);
  float*  vtb  = (float*)(ws + oVT);
  float*  att  = (float*)(ws + oATT);
  __bf16* wgut = (__bf16*)(ws + oWGUT);
  __bf16* wdt  = (__bf16*)(ws + oWDT);
  __bf16* sgut = (__bf16*)(ws + oSGUT);
  __bf16* sdt  = (__bf16*)(ws + oSDT);
  float*  gu   = (float*)(ws + oGU);
  __bf16* hb   = (__bf16*)(ws + oHB);
  float*  ybuf = (float*)(ws + oY);
  float*  sgu  = (float*)(ws + oSGU);
  __bf16* shb  = (__bf16*)(ws + oSHB);
  float*  sdb  = (float*)(ws + oSDB);
  int*   eidx = (int*)(ws + oEIDX);
  float* ew   = (float*)(ws + oEW);
  int*   slot = (int*)(ws + oSLOT);
  int*   list = (int*)(ws + oLIST);
  int*   cnt  = (int*)(ws + oCNT);
  int*   offs = (int*)(ws + oOFF);
  int*   curs = (int*)(ws + oCUR);

  const long S22 = (long)2048*2048, S21 = (long)2048*1024;

  // --- attention weight transposes (f32 -> f32 [N,K]) ---
  transpose_kernel<float><<<dim3(32,32,1), 256, 0, stream>>>(wq, wqkvT,          2048, 2048, 1, 0, 0, 0);
  transpose_kernel<float><<<dim3(32,32,1), 256, 0, stream>>>(wk, wqkvT + S22,    2048, 2048, 1, 0, 0, 0);
  transpose_kernel<float><<<dim3(32,32,1), 256, 0, stream>>>(wv, wqkvT + 2*S22,  2048, 2048, 1, 0, 0, 0);
  transpose_kernel<float><<<dim3(32,32,1), 256, 0, stream>>>(wo, woT,            2048, 2048, 1, 0, 0, 0);

  // --- attention ---
  rmsnorm_kernel<float><<<1024, 256, 0, stream>>>(hid, ln1, xn1);

  // fused QKV: [1024,2048] x [6144,2048]^T -> qkv [1024,6144]
  gemm_kernel<0, true, false, false, false><<<dim3(48,8,1), 256, 0, stream>>>(
      xn1, wqkvT, qkv, nullptr, 1024, 6144, 2048, 2048, 2048, 6144,
      1, 0, 0, 0, 0, 0, 0, nullptr, nullptr, nullptr);

  rope_kernel<<<4096, 256, 0, stream>>>(qkv);

  // V^T per (b,h): qkv v-part [512,128] (row stride 6144) -> vtb [32][128][512]
  transpose_kernel<float><<<dim3(2,8,32), 256, 0, stream>>>(
      qkv + 4096, vtb, 6144, 512, 16, (long)512*6144, 128, (long)128*512);

  // scores = Q @ K^T, causal tile-skip, 32 (b,h) batches
  gemm_kernel<0, true, false, true, false><<<dim3(4,4,32), 256, 0, stream>>>(
      qkv, qkv + 2048, scf, nullptr, 512, 512, 128, 6144, 6144, 512,
      16, (long)512*6144, 128, (long)512*6144, 128, (long)16*512*512, (long)512*512,
      nullptr, nullptr, nullptr);

  softmax_kernel<<<16384, 256, 0, stream>>>(scf);

  // attn = P @ V (K-early-stop), B = vtb pre-transposed
  gemm_kernel<0, true, false, false, true><<<dim3(1,4,32), 256, 0, stream>>>(
      scf, vtb, att, nullptr, 512, 128, 512, 512, 512, 2048,
      16, (long)16*512*512, (long)512*512, (long)16*128*512, (long)128*512,
      (long)512*2048, 128, nullptr, nullptr, nullptr);

  // h2 = hidden + attn @ wo
  gemm_kernel<0, true, true, false, false><<<dim3(16,8,1), 256, 0, stream>>>(
      att, woT, h2, hid, 1024, 2048, 2048, 2048, 2048, 2048,
      1, 0, 0, 0, 0, 0, 0, nullptr, nullptr, nullptr);

  // --- routing ---
  rmsnorm_kernel<__bf16><<<1024, 256, 0, stream>>>(h2, ln2, xb2);
  zero8_kernel<<<1, 64, 0, stream>>>(cnt);
  routing_kernel<<<1024, 256, 0, stream>>>(h2, ln2, gw, gb, eidx, ew, cnt);
  scan_kernel<<<1, 64, 0, stream>>>(cnt, offs, curs);
  scatter_kernel<<<4, 256, 0, stream>>>(eidx, offs, curs, list, slot);

  // --- MoE weight transposes (f32 -> bf16 [N,K]), overlaying dead attention buffers ---
  transpose_kernel<__bf16><<<dim3(16,32,8), 256, 0, stream>>>(wgat, wgut,        1024, 2048, 1, S21, 0, S22);
  transpose_kernel<__bf16><<<dim3(16,32,8), 256, 0, stream>>>(wup,  wgut + S21,  1024, 2048, 1, S21, 0, S22);
  transpose_kernel<__bf16><<<dim3(32,16,8), 256, 0, stream>>>(wdn,  wdt,         2048, 1024, 1, S21, 0, S21);
  transpose_kernel<__bf16><<<dim3(16,32,1), 256, 0, stream>>>(swg,  sgut,        1024, 2048, 1, 0, 0, 0);
  transpose_kernel<__bf16><<<dim3(16,32,1), 256, 0, stream>>>(swu,  sgut + S21,  1024, 2048, 1, 0, 0, 0);
  transpose_kernel<__bf16><<<dim3(32,16,1), 256, 0, stream>>>(swd,  sdt,         2048, 1024, 1, 0, 0, 0);

  // --- routed experts: fused gate|up then down ---
  gemm_kernel<1, false, false, false, false><<<dim3(16,8,8), 256, 0, stream>>>(
      xb2, wgut, gu, nullptr, 1024, 2048, 2048, 2048, 2048, 2048,
      1, 0, 0, S22, 0, 0, 0, cnt, offs, list);
  silumul_kernel<<<8192, 256, 0, stream>>>(gu, hb, 2048*1024);
  gemm_kernel<2, false, false, false, false><<<dim3(16,8,8), 256, 0, stream>>>(
      hb, wdt, ybuf, nullptr, 1024, 2048, 1024, 1024, 1024, 2048,
      1, 0, 0, S21, 0, 0, 0, cnt, offs, nullptr);

  // --- shared expert (wgut dead -> sgu region reuse is safe) ---
  gemm_kernel<0, false, false, false, false><<<dim3(16,8,1), 256, 0, stream>>>(
      xb2, sgut, sgu, nullptr, 1024, 2048, 2048, 2048, 2048, 2048,
      1, 0, 0, 0, 0, 0, 0, nullptr, nullptr, nullptr);
  silumul_kernel<<<4096, 256, 0, stream>>>(sgu, shb, 1024*1024);
  gemm_kernel<0, false, false, false, false><<<dim3(16,8,1), 256, 0, stream>>>(
      shb, sdt, sdb, nullptr, 1024, 2048, 1024, 1024, 1024, 2048,
      1, 0, 0, 0, 0, 0, 0, nullptr, nullptr, nullptr);

  // --- combine ---
  combine_kernel<<<8192, 256, 0, stream>>>(h2, ybuf, sdb, slot, ew, out);
}

// Round 4
// 971.124 us; speedup vs baseline: 2.4770x; 1.1912x over previous
//
#include <hip/hip_runtime.h>

typedef __bf16 bf16x4 __attribute__((ext_vector_type(4)));
typedef __bf16 bf16x8 __attribute__((ext_vector_type(8)));
typedef float  f32x4  __attribute__((ext_vector_type(4)));

#define THREADS 256
constexpr int BM = 128, BN = 128, BK = 32, BKP = 40;

// ---- workspace layout (bytes), total <=160 MB ----
constexpr size_t MB = 1024*1024;
// persistent
constexpr size_t oH2    = 0;            // f32 [1024,2048] 8MB
constexpr size_t oXB2   = 8*MB;         // bf16 [1024,2048] 4MB
constexpr size_t oRT    = 12*MB;        // routing scratch (1MB)
// attention phase
constexpr size_t oWQKVT = 16*MB;        // bf16 hi [6144,2048] 24MB
constexpr size_t oWQKVL = 40*MB;        // bf16 lo 24MB
constexpr size_t oWOT   = 64*MB;        // bf16 hi [2048,2048] 8MB
constexpr size_t oWOL   = 72*MB;        // bf16 lo 8MB
constexpr size_t oXN1   = 80*MB;        // bf16 hi [1024,2048] 4MB
constexpr size_t oXN1L  = 84*MB;        // bf16 lo 4MB
constexpr size_t oQKV   = 88*MB;        // f32 [1024,6144] 24MB (dead after rope/VT)
constexpr size_t oSCF   = 112*MB;       // f32 [32,512,512] 32MB (dead after softmax)
constexpr size_t oQKS   = 144*MB;       // bf16 hi [1024,4096] 8MB (rotated q,k)
constexpr size_t oQKSL  = 152*MB;       // bf16 lo 8MB
// overlays (dead wqkvT after QKV gemm)
constexpr size_t oVT    = 16*MB;        // bf16 hi [32,128,512] 4MB
constexpr size_t oVTL   = 20*MB;        // bf16 lo 4MB
constexpr size_t oATT   = 24*MB;        // f32 [1024,2048] 8MB
constexpr size_t oPB    = 40*MB;        // bf16 hi [32,512,512] 16MB (over wqkv lo)
constexpr size_t oPBL   = 56*MB;        // bf16 lo 16MB... (56..72 overlaps oWOT!)
// careful: oPBL must not hit woT (64..80). Put pb_lo split: use 88..104 (qkv dead by softmax time)
constexpr size_t oPBL2  = 88*MB;        // bf16 lo [32,512,512] 16MB (over dead qkv)
// MoE phase (after wo gemm everything 16..160 except none needed)
constexpr size_t oWGUT  = 16*MB;        // bf16 [8,2048,2048] 64MB
constexpr size_t oWDT   = 80*MB;        // bf16 [8,2048,1024] 32MB
constexpr size_t oSGUT  = 112*MB;       // bf16 [2048,2048] 8MB
constexpr size_t oSDT   = 120*MB;       // bf16 [2048,1024] 4MB
constexpr size_t oGU    = 124*MB;       // f32 [2048,2048] 16MB
constexpr size_t oHB    = 140*MB;       // bf16 [2048,1024] 4MB
constexpr size_t oY     = 144*MB;       // f32 [2048,2048] 16MB
constexpr size_t oSGU   = 16*MB;        // f32 [1024,2048] 8MB (wgut dead after routed-gu)
constexpr size_t oSHB   = 24*MB;        // bf16 [1024,1024] 2MB
constexpr size_t oSDB   = 26*MB;        // f32 [1024,2048] 8MB
// routing arrays
constexpr size_t oEIDX = oRT;
constexpr size_t oEW   = oRT + 8192;
constexpr size_t oSLOT = oRT + 16384;
constexpr size_t oLIST = oRT + 24576;
constexpr size_t oCNT  = oRT + 32768;
constexpr size_t oOFF  = oRT + 33024;
constexpr size_t oCUR  = oRT + 33280;

__device__ __forceinline__ bf16x8 bzero8() {
  bf16x8 z;
#pragma unroll
  for (int j = 0; j < 8; ++j) z[j] = (__bf16)0.f;
  return z;
}

// ---- 64x64 LDS tile transpose. OM: 1 = bf16 out, 2 = bf16 hi/lo planes ----
template<int OM>
__global__ void transpose_kernel(const float* __restrict__ in, __bf16* __restrict__ out,
                                 int ldin, int ldout, int zlo,
                                 long inBH, long inBL, long outB, long plane) {
  __shared__ float tile[64][65];
  int z = blockIdx.z;
  const float* inp = in + (long)(z / zlo) * inBH + (long)(z % zlo) * inBL;
  __bf16* outp = out + (long)z * outB;
  int r0 = blockIdx.y * 64, c0 = blockIdx.x * 64;
  int tid = threadIdx.x;
#pragma unroll
  for (int i = 0; i < 4; ++i) {
    int lin = tid + i * 256;
    int r = lin >> 4, c4 = (lin & 15) << 2;
    f32x4 v = *(const f32x4*)(inp + (long)(r0 + r) * ldin + c0 + c4);
    tile[r][c4] = v[0]; tile[r][c4+1] = v[1]; tile[r][c4+2] = v[2]; tile[r][c4+3] = v[3];
  }
  __syncthreads();
#pragma unroll
  for (int i = 0; i < 4; ++i) {
    int lin = tid + i * 256;
    int oR = lin >> 4, oC4 = (lin & 15) << 2;
    bf16x4 hi, lo;
#pragma unroll
    for (int j = 0; j < 4; ++j) {
      float v = tile[oC4 + j][oR];
      hi[j] = (__bf16)v;
      if constexpr (OM == 2) lo[j] = (__bf16)(v - (float)hi[j]);
    }
    __bf16* dst = outp + (long)(c0 + oR) * ldout + r0 + oC4;
    *(bf16x4*)dst = hi;
    if constexpr (OM == 2) *(bf16x4*)(dst + plane) = lo;
  }
}

// MODE 0: batched strided; MODE 1: gathered A rows; MODE 2: dense A rows at offsets
// SP 0: single bf16 A,B (1-term MFMA)
// SP 1: A f32 on-the-fly split, B pre-split bf16 planes (3-term)
// SP 2: A pre-split planes, B pre-split planes (3-term)
template<int MODE, int SP, bool RESID, bool CAUSAL, bool KTRI>
__global__ __launch_bounds__(256, 2)
void gemm_kernel(const void* __restrict__ Av, const void* __restrict__ Bv, float* __restrict__ C,
                 const float* __restrict__ Rres,
                 int M, int N, int K, int lda, int ldb, int ldc,
                 int zlo, long aHi, long aLo, long bHi, long bLo, long cHi, long cLo,
                 long aPlane, long bPlane,
                 const int* __restrict__ counts, const int* __restrict__ offsets,
                 const int* __restrict__ gather) {
  const int n0 = blockIdx.x * BN;
  const int m0 = blockIdx.y * BM;
  const int z  = blockIdx.z;
  if (CAUSAL && n0 > m0) return;   // fully-masked score tile

  const float*  Af = (const float*)Av;
  const __bf16* Ah = (const __bf16*)Av;
  const __bf16* Bh = (const __bf16*)Bv;

  int mcount; int rowbase = 0;
  long aoff = 0, boff = 0, coff = 0;
  if constexpr (MODE == 0) {
    mcount = M;
    int zh = z / zlo, zl = z % zlo;
    aoff = (long)zh*aHi + (long)zl*aLo;
    boff = (long)zh*bHi + (long)zl*bLo;
    coff = (long)zh*cHi + (long)zl*cLo;
  } else {
    mcount = counts[z];
    rowbase = offsets[z];
    if (m0 >= mcount) return;
    boff = (long)z*bHi;
  }

  constexpr bool TRI = (SP != 0);
  constexpr int ABUF = BM*BKP;
  constexpr int BBUF = BN*BKP;
  __shared__ __align__(16) __bf16 As[(TRI?2:1)*ABUF];
  __shared__ __align__(16) __bf16 Bs[(TRI?2:1)*BBUF];

  const int tid = threadIdx.x;
  const int lane = tid & 63, wave = tid >> 6;
  const int wm = wave >> 1, wn = wave & 1;
  const int lq = lane >> 4, lr = lane & 15;

  int kend = K;
  if (KTRI) { int ke = m0 + BM; kend = ke < K ? ke : K; }

  f32x4 acc[4][4] = {};

  for (int k0 = 0; k0 < kend; k0 += BK) {
    if (k0) __syncthreads();
    // ---- stage A tile [BM][BK] ----
    if constexpr (SP == 1) {
      // f32 on-the-fly split
#pragma unroll
      for (int it = 0; it < 4; ++it) {
        int lin = tid + it*THREADS;
        int row = lin >> 3;
        int c4  = (lin & 7) << 2;
        int gr  = m0 + row;
        bf16x4 hi, lo;
#pragma unroll
        for (int j = 0; j < 4; ++j) { hi[j]=(__bf16)0.f; lo[j]=(__bf16)0.f; }
        if (gr < mcount) {
          long arow = gr;
          f32x4 v = *(const f32x4*)(Af + aoff + arow*(long)lda + k0 + c4);
#pragma unroll
          for (int j = 0; j < 4; ++j) {
            hi[j] = (__bf16)v[j];
            lo[j] = (__bf16)(v[j] - (float)hi[j]);
          }
        }
        *(bf16x4*)(As + row*BKP + c4) = hi;
        *(bf16x4*)(As + ABUF + row*BKP + c4) = lo;
      }
    } else {
      // bf16 (single or pre-split planes)
#pragma unroll
      for (int it = 0; it < 2; ++it) {
        int lin = tid + it*THREADS;
        int row = lin >> 2;
        int c8  = (lin & 3) << 3;
        int gr  = m0 + row;
        bf16x8 hi = bzero8(), lo;
        if constexpr (SP == 2) lo = bzero8();
        if (gr < mcount) {
          long arow;
          if constexpr (MODE == 1) arow = gather[rowbase + gr];
          else if constexpr (MODE == 2) arow = rowbase + gr;
          else arow = gr;
          const __bf16* p = Ah + aoff + arow*(long)lda + k0 + c8;
          hi = *(const bf16x8*)p;
          if constexpr (SP == 2) lo = *(const bf16x8*)(p + aPlane);
        }
        *(bf16x8*)(As + row*BKP + c8) = hi;
        if constexpr (SP == 2) *(bf16x8*)(As + ABUF + row*BKP + c8) = lo;
      }
    }
    // ---- stage B tile [BN][BK] (always bf16, pre-transposed [N,K]) ----
#pragma unroll
    for (int it = 0; it < 2; ++it) {
      int lin = tid + it*THREADS;
      int row = lin >> 2;
      int c8  = (lin & 3) << 3;
      const __bf16* p = Bh + boff + (long)(n0+row)*ldb + k0 + c8;
      *(bf16x8*)(Bs + row*BKP + c8) = *(const bf16x8*)p;
      if constexpr (TRI) *(bf16x8*)(Bs + BBUF + row*BKP + c8) = *(const bf16x8*)(p + bPlane);
    }
    __syncthreads();

    bf16x8 fa[4], fal[4];
    const __bf16* ap = As + (wm*64 + lr)*BKP + lq*8;
    const __bf16* bp = Bs + (wn*64 + lr)*BKP + lq*8;
#pragma unroll
    for (int i = 0; i < 4; ++i) {
      fa[i] = *(const bf16x8*)(ap + i*16*BKP);
      if constexpr (TRI) fal[i] = *(const bf16x8*)(ap + ABUF + i*16*BKP);
    }
#pragma unroll
    for (int j = 0; j < 4; ++j) {
      bf16x8 fb = *(const bf16x8*)(bp + j*16*BKP);
      if constexpr (TRI) {
        bf16x8 fbl = *(const bf16x8*)(bp + BBUF + j*16*BKP);
#pragma unroll
        for (int i = 0; i < 4; ++i) {
          acc[i][j] = __builtin_amdgcn_mfma_f32_16x16x32_bf16(fa[i],  fbl, acc[i][j], 0, 0, 0);
          acc[i][j] = __builtin_amdgcn_mfma_f32_16x16x32_bf16(fal[i], fb,  acc[i][j], 0, 0, 0);
          acc[i][j] = __builtin_amdgcn_mfma_f32_16x16x32_bf16(fa[i],  fb,  acc[i][j], 0, 0, 0);
        }
      } else {
#pragma unroll
        for (int i = 0; i < 4; ++i)
          acc[i][j] = __builtin_amdgcn_mfma_f32_16x16x32_bf16(fa[i], fb, acc[i][j], 0, 0, 0);
      }
    }
  }

  // epilogue: C/D layout col=lane&15, row=(lane>>4)*4+reg
#pragma unroll
  for (int i = 0; i < 4; ++i) {
#pragma unroll
    for (int rg = 0; rg < 4; ++rg) {
      int lrow = wm*64 + i*16 + lq*4 + rg;
      int gr = m0 + lrow;
      if (gr < mcount) {
        long crow = coff + (long)(rowbase + gr)*ldc;
#pragma unroll
        for (int j = 0; j < 4; ++j) {
          int col = n0 + wn*64 + j*16 + lr;
          float val = acc[i][j][rg];
          if constexpr (RESID) val += Rres[(long)gr*ldc + col];
          C[crow + col] = val;
        }
      }
    }
  }
}

// OM 1: bf16 out; OM 2: bf16 hi/lo planes
template<int OM>
__global__ void rmsnorm_kernel(const float* __restrict__ x, const float* __restrict__ w,
                               __bf16* __restrict__ out, long plane) {
  const int row = blockIdx.x;
  const float* xr = x + (long)row * 2048;
  float ss = 0.f;
  for (int d = threadIdx.x; d < 2048; d += 256) { float v = xr[d]; ss += v*v; }
  __shared__ float red[4];
  int lane = threadIdx.x & 63, wave = threadIdx.x >> 6;
#pragma unroll
  for (int off = 32; off; off >>= 1) ss += __shfl_down(ss, off, 64);
  if (lane == 0) red[wave] = ss;
  __syncthreads();
  float tot = red[0] + red[1] + red[2] + red[3];
  float rs = rsqrtf(tot * (1.f/2048.f) + 1e-6f);
  __bf16* orow = out + (long)row * 2048;
  for (int d = threadIdx.x; d < 2048; d += 256) {
    float v = xr[d]*rs*w[d];
    __bf16 h = (__bf16)v;
    orow[d] = h;
    if constexpr (OM == 2) orow[d + plane] = (__bf16)(v - (float)h);
  }
}

// RoPE q,k from qkv f32 [1024,6144] -> rotated hi/lo bf16 [1024,4096] (q cols 0..2047, k 2048..4095)
__global__ void rope_split_kernel(const float* __restrict__ qkv, __bf16* __restrict__ o, long plane) {
  int tid = blockIdx.x*256 + threadIdx.x;   // 1024*16*64 threads
  int i = tid & 63;
  int th = tid >> 6;
  int h = th & 15;
  int t = th >> 4;
  int s = t & 511;
  long ib = (long)t*6144 + h*128;
  long ob = (long)t*4096 + h*128;
  float inv = 1.f / powf(10000.f, (float)i * (1.f/64.f));
  float ang = (float)s * inv;
  float c = cosf(ang), sn = sinf(ang);
  float q1 = qkv[ib+i], q2 = qkv[ib+64+i];
  float r1 = q1*c - q2*sn, r2 = q2*c + q1*sn;
  __bf16 h1 = (__bf16)r1, h2v = (__bf16)r2;
  o[ob+i] = h1;            o[ob+i+plane] = (__bf16)(r1 - (float)h1);
  o[ob+64+i] = h2v;        o[ob+64+i+plane] = (__bf16)(r2 - (float)h2v);
  float k1 = qkv[ib+2048+i], k2 = qkv[ib+2048+64+i];
  float s1 = k1*c - k2*sn, s2 = k2*c + k1*sn;
  __bf16 g1 = (__bf16)s1, g2 = (__bf16)s2;
  o[ob+2048+i] = g1;       o[ob+2048+i+plane] = (__bf16)(s1 - (float)g1);
  o[ob+2048+64+i] = g2;    o[ob+2048+64+i+plane] = (__bf16)(s2 - (float)g2);
}

// causal softmax: scf f32 -> P hi/lo bf16
__global__ void softmax_kernel(const float* __restrict__ sc, __bf16* __restrict__ p, long plane) {
  int r = blockIdx.x & 511;
  long bh = blockIdx.x >> 9;
  const float scale = 0.08838834764831845f;   // 1/sqrt(128)
  long base = (bh*512 + r)*512;
  int c0 = threadIdx.x, c1 = threadIdx.x + 256;
  float v0 = (c0 <= r) ? sc[base+c0]*scale : -3.0e38f;
  float v1 = (c1 <= r) ? sc[base+c1]*scale : -3.0e38f;
  float m = fmaxf(v0, v1);
  __shared__ float red[4];
  int lane = threadIdx.x & 63, wave = threadIdx.x >> 6;
#pragma unroll
  for (int off = 32; off; off >>= 1) m = fmaxf(m, __shfl_xor(m, off, 64));
  if (lane == 0) red[wave] = m;
  __syncthreads();
  m = fmaxf(fmaxf(red[0], red[1]), fmaxf(red[2], red[3]));
  __syncthreads();
  float e0 = (c0 <= r) ? expf(v0 - m) : 0.f;
  float e1 = (c1 <= r) ? expf(v1 - m) : 0.f;
  float s = e0 + e1;
#pragma unroll
  for (int off = 32; off; off >>= 1) s += __shfl_xor(s, off, 64);
  if (lane == 0) red[wave] = s;
  __syncthreads();
  s = red[0] + red[1] + red[2] + red[3];
  float inv = 1.f / s;
  float p0 = e0*inv, p1 = e1*inv;
  __bf16 h0 = (__bf16)p0, h1 = (__bf16)p1;
  p[base+c0] = h0; p[base+c0+plane] = (__bf16)(p0 - (float)h0);
  p[base+c1] = h1; p[base+c1+plane] = (__bf16)(p1 - (float)h1);
}

__global__ void zero8_kernel(int* c) { if (threadIdx.x < 8) c[threadIdx.x] = 0; }

__global__ void routing_kernel(const float* __restrict__ h2, const float* __restrict__ ln2w,
                               const float* __restrict__ gw, const float* __restrict__ gb,
                               int* __restrict__ eidx, float* __restrict__ ew,
                               int* __restrict__ counts) {
  int t = blockIdx.x;
  const float* xr = h2 + (long)t*2048;
  int lane = threadIdx.x & 63, wave = threadIdx.x >> 6;
  float ss = 0.f;
  for (int d = threadIdx.x; d < 2048; d += 256) { float v = xr[d]; ss += v*v; }
  __shared__ float red[4];
#pragma unroll
  for (int off = 32; off; off >>= 1) ss += __shfl_down(ss, off, 64);
  if (lane == 0) red[wave] = ss;
  __syncthreads();
  float rs = rsqrtf((red[0]+red[1]+red[2]+red[3]) * (1.f/2048.f) + 1e-6f);
  __shared__ float lg[8];
  for (int e = wave; e < 8; e += 4) {
    const float* wr = gw + (long)e*2048;
    float acc = 0.f;
    for (int d = lane; d < 2048; d += 64) acc += (xr[d]*rs*ln2w[d]) * wr[d];
#pragma unroll
    for (int off = 32; off; off >>= 1) acc += __shfl_down(acc, off, 64);
    if (lane == 0) lg[e] = acc;
  }
  __syncthreads();
  if (threadIdx.x == 0) {
    float sg[8], sc[8];
#pragma unroll
    for (int e = 0; e < 8; ++e) { sg[e] = 1.f/(1.f+expf(-lg[e])); sc[e] = sg[e] + gb[e]; }
    float gs[2];
#pragma unroll
    for (int g = 0; g < 2; ++g) {
      float m1 = -3e38f, m2 = -3e38f;
#pragma unroll
      for (int j = 0; j < 4; ++j) {
        float v = sc[4*g+j];
        if (v > m1) { m2 = m1; m1 = v; } else if (v > m2) m2 = v;
      }
      gs[g] = m1 + m2;
    }
    int b4 = (gs[1] > gs[0]) ? 4 : 0;
    int i1 = 0; float v1 = -3e38f;
#pragma unroll
    for (int j = 0; j < 4; ++j) if (sc[b4+j] > v1) { v1 = sc[b4+j]; i1 = j; }
    int i2 = -1; float v2 = -3e38f;
#pragma unroll
    for (int j = 0; j < 4; ++j) if (j != i1 && sc[b4+j] > v2) { v2 = sc[b4+j]; i2 = j; }
    float w1 = sg[b4+i1], w2 = sg[b4+i2], s = w1 + w2;
    eidx[t*2] = b4+i1; eidx[t*2+1] = b4+i2;
    ew[t*2] = w1/s;    ew[t*2+1] = w2/s;
    atomicAdd(&counts[b4+i1], 1); atomicAdd(&counts[b4+i2], 1);
  }
}

__global__ void scan_kernel(const int* __restrict__ counts, int* __restrict__ offsets,
                            int* __restrict__ cursors) {
  if (threadIdx.x == 0 && blockIdx.x == 0) {
    int s = 0;
    for (int e = 0; e < 8; ++e) { offsets[e] = s; s += counts[e]; cursors[e] = 0; }
    offsets[8] = s;
  }
}

__global__ void scatter_kernel(const int* __restrict__ eidx, const int* __restrict__ offsets,
                               int* __restrict__ cursors, int* __restrict__ list,
                               int* __restrict__ slot) {
  int t = blockIdx.x*256 + threadIdx.x;
  if (t < 1024) {
#pragma unroll
    for (int kk = 0; kk < 2; ++kk) {
      int e = eidx[t*2+kk];
      int pos = atomicAdd(&cursors[e], 1);
      int g = offsets[e] + pos;
      list[g] = t;
      slot[t*2+kk] = g;
    }
  }
}

// fused gate|up: gu[s][0:1024]=gate, gu[s][1024:2048]=up -> hb[s][0:1024]
__global__ void silumul_kernel(const float* __restrict__ gu, __bf16* __restrict__ o, int n) {
  int i = blockIdx.x*256 + threadIdx.x;
  if (i < n) {
    int s = i >> 10, j = i & 1023;
    float gv = gu[(long)s*2048 + j];
    float uv = gu[(long)s*2048 + 1024 + j];
    float sg = gv / (1.f + expf(-gv));
    o[i] = (__bf16)(sg * uv);
  }
}

__global__ void combine_kernel(const float* __restrict__ h2, const float* __restrict__ y,
                               const float* __restrict__ sdown, const int* __restrict__ slot,
                               const float* __restrict__ ew, float* __restrict__ out) {
  int i = blockIdx.x*256 + threadIdx.x;   // < 1024*2048
  int t = i >> 11;
  int d = i & 2047;
  float rv = ew[t*2]   * y[(long)slot[t*2]  *2048 + d]
           + ew[t*2+1] * y[(long)slot[t*2+1]*2048 + d];
  out[i] = h2[i] + sdown[i] + 2.5f * rv;
}

extern "C" void kernel_launch(void* const* d_in, const int* in_sizes, int n_in,
                              void* d_out, int out_size, void* d_ws, size_t ws_size,
                              hipStream_t stream) {
  const float* hid  = (const float*)d_in[0];
  const float* ln1  = (const float*)d_in[1];
  const float* ln2  = (const float*)d_in[2];
  const float* wq   = (const float*)d_in[3];
  const float* wk   = (const float*)d_in[4];
  const float* wv   = (const float*)d_in[5];
  const float* wo   = (const float*)d_in[6];
  const float* gw   = (const float*)d_in[7];
  const float* gb   = (const float*)d_in[8];
  const float* wgat = (const float*)d_in[9];
  const float* wup  = (const float*)d_in[10];
  const float* wdn  = (const float*)d_in[11];
  const float* swg  = (const float*)d_in[12];
  const float* swu  = (const float*)d_in[13];
  const float* swd  = (const float*)d_in[14];
  float* out = (float*)d_out;
  char* ws = (char*)d_ws;

  float*  h2    = (float*)(ws + oH2);
  __bf16* xb2   = (__bf16*)(ws + oXB2);
  __bf16* wqkvT = (__bf16*)(ws + oWQKVT);
  __bf16* woT   = (__bf16*)(ws + oWOT);
  __bf16* xn1   = (__bf16*)(ws + oXN1);
  float*  qkv   = (float*)(ws + oQKV);
  float*  scf   = (float*)(ws + oSCF);
  __bf16* qks   = (__bf16*)(ws + oQKS);
  __bf16* vtb   = (__bf16*)(ws + oVT);
  float*  att   = (float*)(ws + oATT);
  __bf16* pb    = (__bf16*)(ws + oPB);
  __bf16* wgut  = (__bf16*)(ws + oWGUT);
  __bf16* wdt   = (__bf16*)(ws + oWDT);
  __bf16* sgut  = (__bf16*)(ws + oSGUT);
  __bf16* sdt   = (__bf16*)(ws + oSDT);
  float*  gu    = (float*)(ws + oGU);
  __bf16* hb    = (__bf16*)(ws + oHB);
  float*  ybuf  = (float*)(ws + oY);
  float*  sgu   = (float*)(ws + oSGU);
  __bf16* shb   = (__bf16*)(ws + oSHB);
  float*  sdb   = (float*)(ws + oSDB);
  int*   eidx = (int*)(ws + oEIDX);
  float* ew   = (float*)(ws + oEW);
  int*   slot = (int*)(ws + oSLOT);
  int*   list = (int*)(ws + oLIST);
  int*   cnt  = (int*)(ws + oCNT);
  int*   offs = (int*)(ws + oOFF);
  int*   curs = (int*)(ws + oCUR);

  const long S22 = (long)2048*2048, S21 = (long)2048*1024;
  const long pWQKV = (oWQKVL - oWQKVT) / 2;   // 12,582,912 elements
  const long pWO   = (oWOL - oWOT) / 2;       // 4,194,304
  const long pXN1  = 2*MB;                    // 4MB/2B
  const long pQKS  = (oQKSL - oQKS) / 2;      // 4,194,304
  const long pVT   = 2*MB;
  const long pPB   = (oPBL2 - oPB) / 2;       // 24MB/2B = 25,165,824

  // --- attention weight transposes: f32 [D,N] -> bf16 hi/lo [N,D] ---
  transpose_kernel<2><<<dim3(32,32,1), 256, 0, stream>>>(wq, wqkvT,          2048, 2048, 1, 0, 0, 0, pWQKV);
  transpose_kernel<2><<<dim3(32,32,1), 256, 0, stream>>>(wk, wqkvT + S22,    2048, 2048, 1, 0, 0, 0, pWQKV);
  transpose_kernel<2><<<dim3(32,32,1), 256, 0, stream>>>(wv, wqkvT + 2*S22,  2048, 2048, 1, 0, 0, 0, pWQKV);
  transpose_kernel<2><<<dim3(32,32,1), 256, 0, stream>>>(wo, woT,            2048, 2048, 1, 0, 0, 0, pWO);

  // --- attention ---
  rmsnorm_kernel<2><<<1024, 256, 0, stream>>>(hid, ln1, xn1, pXN1);

  // fused QKV: [1024,2048] x [6144,2048]^T -> qkv f32 [1024,6144]  (SP=2)
  gemm_kernel<0, 2, false, false, false><<<dim3(48,8,1), 256, 0, stream>>>(
      xn1, wqkvT, qkv, nullptr, 1024, 6144, 2048, 2048, 2048, 6144,
      1, 0, 0, 0, 0, 0, 0, pXN1, pWQKV, nullptr, nullptr, nullptr);

  // RoPE + split q,k -> qks hi/lo [1024,4096]
  rope_split_kernel<<<4096, 256, 0, stream>>>(qkv, qks, pQKS);

  // V^T per (b,h): qkv v-part [512,128] -> vtb hi/lo [32][128][512]
  transpose_kernel<2><<<dim3(2,8,32), 256, 0, stream>>>(
      qkv + 4096, vtb, 6144, 512, 16, (long)512*6144, 128, (long)128*512, pVT);

  // scores = Q @ K^T (SP=2, causal tile-skip)
  gemm_kernel<0, 2, false, true, false><<<dim3(4,4,32), 256, 0, stream>>>(
      qks, qks + 2048, scf, nullptr, 512, 512, 128, 4096, 4096, 512,
      16, (long)512*4096, 128, (long)512*4096, 128, (long)16*512*512, (long)512*512,
      pQKS, pQKS, nullptr, nullptr, nullptr);

  // softmax -> P hi/lo
  softmax_kernel<<<16384, 256, 0, stream>>>(scf, pb, pPB);

  // attn = P @ V (SP=2, K-early-stop)
  gemm_kernel<0, 2, false, false, true><<<dim3(1,4,32), 256, 0, stream>>>(
      pb, vtb, att, nullptr, 512, 128, 512, 512, 512, 2048,
      16, (long)16*512*512, (long)512*512, (long)16*128*512, (long)128*512,
      (long)512*2048, 128, pPB, pVT, nullptr, nullptr, nullptr);

  // h2 = hidden + attn @ wo  (SP=1: A f32 on-the-fly, B pre-split)
  gemm_kernel<0, 1, true, false, false><<<dim3(16,8,1), 256, 0, stream>>>(
      att, woT, h2, hid, 1024, 2048, 2048, 2048, 2048, 2048,
      1, 0, 0, 0, 0, 0, 0, 0, pWO, nullptr, nullptr, nullptr);

  // --- routing ---
  rmsnorm_kernel<1><<<1024, 256, 0, stream>>>(h2, ln2, xb2, 0);
  zero8_kernel<<<1, 64, 0, stream>>>(cnt);
  routing_kernel<<<1024, 256, 0, stream>>>(h2, ln2, gw, gb, eidx, ew, cnt);
  scan_kernel<<<1, 64, 0, stream>>>(cnt, offs, curs);
  scatter_kernel<<<4, 256, 0, stream>>>(eidx, offs, curs, list, slot);

  // --- MoE weight transposes (f32 -> bf16 single [N,K]) ---
  transpose_kernel<1><<<dim3(16,32,8), 256, 0, stream>>>(wgat, wgut,        1024, 2048, 1, S21, 0, S22, 0);
  transpose_kernel<1><<<dim3(16,32,8), 256, 0, stream>>>(wup,  wgut + S21,  1024, 2048, 1, S21, 0, S22, 0);
  transpose_kernel<1><<<dim3(32,16,8), 256, 0, stream>>>(wdn,  wdt,         2048, 1024, 1, S21, 0, S21, 0);
  transpose_kernel<1><<<dim3(16,32,1), 256, 0, stream>>>(swg,  sgut,        1024, 2048, 1, 0, 0, 0, 0);
  transpose_kernel<1><<<dim3(16,32,1), 256, 0, stream>>>(swu,  sgut + S21,  1024, 2048, 1, 0, 0, 0, 0);
  transpose_kernel<1><<<dim3(32,16,1), 256, 0, stream>>>(swd,  sdt,         2048, 1024, 1, 0, 0, 0, 0);

  // --- routed experts: fused gate|up then down ---
  gemm_kernel<1, 0, false, false, false><<<dim3(16,8,8), 256, 0, stream>>>(
      xb2, wgut, gu, nullptr, 1024, 2048, 2048, 2048, 2048, 2048,
      1, 0, 0, S22, 0, 0, 0, 0, 0, cnt, offs, list);
  silumul_kernel<<<8192, 256, 0, stream>>>(gu, hb, 2048*1024);
  gemm_kernel<2, 0, false, false, false><<<dim3(16,8,8), 256, 0, stream>>>(
      hb, wdt, ybuf, nullptr, 1024, 2048, 1024, 1024, 1024, 2048,
      1, 0, 0, S21, 0, 0, 0, 0, 0, cnt, offs, nullptr);

  // --- shared expert ---
  gemm_kernel<0, 0, false, false, false><<<dim3(16,8,1), 256, 0, stream>>>(
      xb2, sgut, sgu, nullptr, 1024, 2048, 2048, 2048, 2048, 2048,
      1, 0, 0, 0, 0, 0, 0, 0, 0, nullptr, nullptr, nullptr);
  silumul_kernel<<<4096, 256, 0, stream>>>(sgu, shb, 1024*1024);
  gemm_kernel<0, 0, false, false, false><<<dim3(16,8,1), 256, 0, stream>>>(
      shb, sdt, sdb, nullptr, 1024, 2048, 1024, 1024, 1024, 2048,
      1, 0, 0, 0, 0, 0, 0, 0, 0, nullptr, nullptr, nullptr);

  // --- combine ---
  combine_kernel<<<8192, 256, 0, stream>>>(h2, ybuf, sdb, slot, ew, out);
}